// Round 1
// baseline (551.282 us; speedup 1.0000x reference)
//
#include <hip/hip_runtime.h>
#include <math.h>

#define HW 3136
#define NC 192
#define NBATCH 16
#define NHEADS 6
#define IMG 56
#define ATT_SCALE 0.17677669529663687f  // 32^-0.5

// Y[n,d,hw] = sum_c X[n,c,hw] * W[c,d] (+ bias[d])
// X: [N, 192, HW], W: [192, M], Y: [N, M, HW]
// grid: (NHW/64, ceil(M/64)), block 256. 64 pos x 64 outch tile, 4x4/thread.
__global__ __launch_bounds__(256) void gemm_ncp(
    const float* __restrict__ X, const float* __restrict__ W,
    const float* __restrict__ bias, float* __restrict__ Y, int M)
{
    __shared__ float Xs[16][64];
    __shared__ float Ws[16][64];
    int t = threadIdx.x;
    int p0 = blockIdx.x * 64;          // global position tile start
    int n = p0 / HW;
    int hw0 = p0 % HW;                 // HW % 64 == 0 -> tile within one n
    int d0 = blockIdx.y * 64;
    const float* Xn = X + (size_t)n * NC * HW;

    int lr = t >> 6;                   // 0..3
    int lc = t & 63;                   // 0..63
    int ty = t >> 4;                   // 0..15 -> out-channel sub
    int tx = t & 15;                   // 0..15 -> position sub

    float acc[4][4] = {};

    for (int k0 = 0; k0 < NC; k0 += 16) {
#pragma unroll
        for (int i = 0; i < 4; ++i)
            Xs[lr + 4 * i][lc] = Xn[(size_t)(k0 + lr + 4 * i) * HW + hw0 + lc];
#pragma unroll
        for (int i = 0; i < 4; ++i) {
            int d = d0 + lc;
            Ws[lr + 4 * i][lc] = (d < M) ? W[(size_t)(k0 + lr + 4 * i) * M + d] : 0.f;
        }
        __syncthreads();
#pragma unroll
        for (int kk = 0; kk < 16; ++kk) {
            float xr[4], wr[4];
#pragma unroll
            for (int j = 0; j < 4; ++j) xr[j] = Xs[kk][tx * 4 + j];
#pragma unroll
            for (int i = 0; i < 4; ++i) wr[i] = Ws[kk][ty * 4 + i];
#pragma unroll
            for (int i = 0; i < 4; ++i)
#pragma unroll
                for (int j = 0; j < 4; ++j)
                    acc[i][j] += wr[i] * xr[j];
        }
        __syncthreads();
    }

    float* Yn = Y + (size_t)n * M * HW;
#pragma unroll
    for (int i = 0; i < 4; ++i) {
        int d = d0 + ty * 4 + i;
        if (d < M) {
            float b = bias ? bias[d] : 0.f;
#pragma unroll
            for (int j = 0; j < 4; ++j)
                Yn[(size_t)d * HW + hw0 + tx * 4 + j] = acc[i][j] + b;
        }
    }
}

// In-place softmax over l: att[n, 9*hk + l, hw], l=0..8 (hk = head*9+k, ch = head*81+k*9+l = 9*hk+l)
__global__ __launch_bounds__(256) void softmax9(float* __restrict__ att)
{
    int idx = blockIdx.x * 256 + threadIdx.x;       // over 16*54*3136
    int hw = idx % HW;
    int g = idx / HW;                                // n*54 + hk
    int n = g / 54;
    int hk = g % 54;
    size_t base = ((size_t)n * 486 + 9 * hk) * HW + hw;
    float vals[9];
    float m = -1e30f;
#pragma unroll
    for (int l = 0; l < 9; ++l) {
        vals[l] = att[base + (size_t)l * HW];
        m = fmaxf(m, vals[l]);
    }
    float s = 0.f;
#pragma unroll
    for (int l = 0; l < 9; ++l) {
        vals[l] = __expf((vals[l] - m) * ATT_SCALE);
        s += vals[l];
    }
    float r = 1.f / s;
#pragma unroll
    for (int l = 0; l < 9; ++l) att[base + (size_t)l * HW] = vals[l] * r;
}

// Wc[n,head,dlt,hw] = sum_{k: q-o_k in bounds, o_k+dlt in [-1,1]^2} att[q-o_k, head,k, l]
// combining the unfold/fold offsets into a per-position 5x5 stencil weight.
__global__ __launch_bounds__(256) void wcombine(const float* __restrict__ att,
                                                float* __restrict__ Wc)
{
    int idx = blockIdx.x * 256 + threadIdx.x;       // over 16*6*3136
    int hw = idx % HW;
    int g = idx / HW;
    int n = g / NHEADS;
    int head = g % NHEADS;
    int h = hw / IMG, w = hw % IMG;
    float wc[25];
#pragma unroll
    for (int d = 0; d < 25; ++d) wc[d] = 0.f;
    const float* attn = att + ((size_t)n * 486 + head * 81) * HW;
#pragma unroll
    for (int k = 0; k < 9; ++k) {
        int oky = k / 3 - 1, okx = k % 3 - 1;
        int hh = h - oky, ww = w - okx;
        if (hh < 0 || hh >= IMG || ww < 0 || ww >= IMG) continue;
        int phw = hh * IMG + ww;
#pragma unroll
        for (int l = 0; l < 9; ++l) {
            int oly = l / 3 - 1, olx = l % 3 - 1;
            int dy = oly - oky + 2, dx = olx - okx + 2;   // 0..4 compile-time
            wc[dy * 5 + dx] += attn[(size_t)(k * 9 + l) * HW + phw];
        }
    }
    float* outp = Wc + ((size_t)(n * NHEADS + head) * 25) * HW + hw;
#pragma unroll
    for (int d = 0; d < 25; ++d) outp[(size_t)d * HW] = wc[d];
}

// folded[n,c,h,w] = sum_dlt Wc[n,head(c),dlt,hw] * v[n,c,h+dy,w+dx] (zero-pad)
__global__ __launch_bounds__(256) void aggregate(const float* __restrict__ v,
                                                 const float* __restrict__ Wc,
                                                 float* __restrict__ folded)
{
    int idx = blockIdx.x * 256 + threadIdx.x;       // over 16*192*3136
    int hw = idx % HW;
    int g = idx / HW;
    int c = g % NC;
    int n = g / NC;
    int head = c >> 5;
    int h = hw / IMG, w = hw % IMG;
    const float* vn = v + ((size_t)n * NC + c) * HW;
    const float* wcn = Wc + ((size_t)(n * NHEADS + head) * 25) * HW + hw;
    float acc = 0.f;
#pragma unroll
    for (int d = 0; d < 25; ++d) {
        int dy = d / 5 - 2, dx = d % 5 - 2;
        int hh = h + dy, ww = w + dx;
        if (hh < 0 || hh >= IMG || ww < 0 || ww >= IMG) continue;
        acc += wcn[(size_t)d * HW] * vn[hh * IMG + ww];
    }
    folded[(size_t)g * HW + hw] = acc;
}

extern "C" void kernel_launch(void* const* d_in, const int* in_sizes, int n_in,
                              void* d_out, int out_size, void* d_ws, size_t ws_size,
                              hipStream_t stream)
{
    const float* x  = (const float*)d_in[0];
    const float* Wv = (const float*)d_in[1];
    const float* Wa = (const float*)d_in[2];
    const float* ba = (const float*)d_in[3];
    const float* Wp = (const float*)d_in[4];
    const float* bp = (const float*)d_in[5];
    float* out = (float*)d_out;

    float* ws   = (float*)d_ws;
    float* v    = ws;                  // 16*192*3136 = 9,633,792 f
    float* att  = v + 9633792;         // 16*486*3136 = 24,385,536 f
    float* Wc   = att + 24385536;      // 16*6*25*3136 = 7,526,400 f
    float* fold = Wc + 7526400;        // 9,633,792 f   (total ~205 MB)

    dim3 blk(256);
    // NHW/64 = 50176/64 = 784 position tiles
    gemm_ncp<<<dim3(784, 3), blk, 0, stream>>>(x, Wv, nullptr, v, 192);
    gemm_ncp<<<dim3(784, 8), blk, 0, stream>>>(x, Wa, ba, att, 486);
    softmax9<<<10584, blk, 0, stream>>>(att);          // 16*54*3136/256
    wcombine<<<1176, blk, 0, stream>>>(att, Wc);       // 16*6*3136/256
    aggregate<<<37632, blk, 0, stream>>>(v, Wc, fold); // 16*192*3136/256
    gemm_ncp<<<dim3(784, 3), blk, 0, stream>>>(fold, Wp, bp, out, 192);
}

// Round 2
// 522.194 us; speedup vs baseline: 1.0557x; 1.0557x over previous
//
#include <hip/hip_runtime.h>
#include <math.h>

#define HW 3136
#define NC 192
#define NBATCH 16
#define NHEADS 6
#define IMG 56
#define ATT_SCALE 0.17677669529663687f  // 32^-0.5

// Y[n,d,hw] = sum_c X[n,c,hw] * W[c,d] (+ bias[d])
// X: [N, 192, HW], W: [192, M], Y: [N, M, HW]
// grid: (NHW/64, ceil(M/64)), block 256. 64 pos x 64 outch tile, 4x4/thread.
__global__ __launch_bounds__(256) void gemm_ncp(
    const float* __restrict__ X, const float* __restrict__ W,
    const float* __restrict__ bias, float* __restrict__ Y, int M)
{
    __shared__ float Xs[16][64];
    __shared__ float Ws[16][64];
    int t = threadIdx.x;
    int p0 = blockIdx.x * 64;          // global position tile start
    int n = p0 / HW;
    int hw0 = p0 % HW;                 // HW % 64 == 0 -> tile within one n
    int d0 = blockIdx.y * 64;
    const float* Xn = X + (size_t)n * NC * HW;

    int lr = t >> 6;                   // 0..3
    int lc = t & 63;                   // 0..63
    int ty = t >> 4;                   // 0..15 -> out-channel sub
    int tx = t & 15;                   // 0..15 -> position sub

    float acc[4][4] = {};

    for (int k0 = 0; k0 < NC; k0 += 16) {
#pragma unroll
        for (int i = 0; i < 4; ++i)
            Xs[lr + 4 * i][lc] = Xn[(size_t)(k0 + lr + 4 * i) * HW + hw0 + lc];
#pragma unroll
        for (int i = 0; i < 4; ++i) {
            int d = d0 + lc;
            Ws[lr + 4 * i][lc] = (d < M) ? W[(size_t)(k0 + lr + 4 * i) * M + d] : 0.f;
        }
        __syncthreads();
#pragma unroll
        for (int kk = 0; kk < 16; ++kk) {
            float xr[4], wr[4];
#pragma unroll
            for (int j = 0; j < 4; ++j) xr[j] = Xs[kk][tx * 4 + j];
#pragma unroll
            for (int i = 0; i < 4; ++i) wr[i] = Ws[kk][ty * 4 + i];
#pragma unroll
            for (int i = 0; i < 4; ++i)
#pragma unroll
                for (int j = 0; j < 4; ++j)
                    acc[i][j] += wr[i] * xr[j];
        }
        __syncthreads();
    }

    float* Yn = Y + (size_t)n * M * HW;
#pragma unroll
    for (int i = 0; i < 4; ++i) {
        int d = d0 + ty * 4 + i;
        if (d < M) {
            float b = bias ? bias[d] : 0.f;
#pragma unroll
            for (int j = 0; j < 4; ++j)
                Yn[(size_t)d * HW + hw0 + tx * 4 + j] = acc[i][j] + b;
        }
    }
}

// Fused: softmax over l (9) + fold/unfold weight-combine (25-tap stencil weights)
// + per-head aggregation over 32 channels.
// Thread = (n, head, hw). att holds RAW logits [N, 486, HW] (bias added by GEMM).
__global__ __launch_bounds__(256) void fused_att_agg(
    const float* __restrict__ att, const float* __restrict__ v,
    float* __restrict__ folded)
{
    int idx = blockIdx.x * 256 + threadIdx.x;   // over N*HEADS*HW = 301056
    int hw = idx % HW;
    int g = idx / HW;
    int head = g % NHEADS;
    int n = g / NHEADS;
    int h = hw / IMG, w = hw % IMG;

    // ---- build the 5x5 data-dependent stencil weights wc[25] ----
    float wc[25];
#pragma unroll
    for (int d = 0; d < 25; ++d) wc[d] = 0.f;
    const float* attn = att + ((size_t)n * 486 + head * 81) * HW;
#pragma unroll
    for (int k = 0; k < 9; ++k) {
        const int oky = k / 3 - 1, okx = k % 3 - 1;
        int hh = h - oky, ww = w - okx;
        if (hh < 0 || hh >= IMG || ww < 0 || ww >= IMG) continue;
        int phw = hh * IMG + ww;
        float a[9];
        float m = -1e30f;
#pragma unroll
        for (int l = 0; l < 9; ++l) {
            a[l] = attn[(size_t)(k * 9 + l) * HW + phw];
            m = fmaxf(m, a[l]);
        }
        float s = 0.f;
#pragma unroll
        for (int l = 0; l < 9; ++l) {
            a[l] = __expf((a[l] - m) * ATT_SCALE);
            s += a[l];
        }
        float r = 1.f / s;
#pragma unroll
        for (int l = 0; l < 9; ++l) {
            const int dy = (l / 3 - 1) - oky + 2;   // 0..4, compile-time
            const int dx = (l % 3 - 1) - okx + 2;
            wc[dy * 5 + dx] += a[l] * r;
        }
    }

    // ---- hoisted bounds: zero invalid taps, clamp offsets to 0 ----
    int voff[25];
#pragma unroll
    for (int d = 0; d < 25; ++d) {
        const int dy = d / 5 - 2, dx = d % 5 - 2;
        int hh = h + dy, ww = w + dx;
        bool ok = (hh >= 0) & (hh < IMG) & (ww >= 0) & (ww < IMG);
        voff[d] = ok ? (dy * IMG + dx) : 0;
        if (!ok) wc[d] = 0.f;
    }

    // ---- aggregate 32 channels of this head ----
    const float* vn = v + ((size_t)n * NC + head * 32) * HW + hw;
    float* on = folded + ((size_t)n * NC + head * 32) * HW + hw;
    for (int c = 0; c < 32; ++c) {
        const float* vp = vn + (size_t)c * HW;
        float acc = 0.f;
#pragma unroll
        for (int d = 0; d < 25; ++d)
            acc += wc[d] * vp[voff[d]];
        on[(size_t)c * HW] = acc;
    }
}

extern "C" void kernel_launch(void* const* d_in, const int* in_sizes, int n_in,
                              void* d_out, int out_size, void* d_ws, size_t ws_size,
                              hipStream_t stream)
{
    const float* x  = (const float*)d_in[0];
    const float* Wv = (const float*)d_in[1];
    const float* Wa = (const float*)d_in[2];
    const float* ba = (const float*)d_in[3];
    const float* Wp = (const float*)d_in[4];
    const float* bp = (const float*)d_in[5];
    float* out = (float*)d_out;

    float* ws   = (float*)d_ws;
    float* v    = ws;                  // 16*192*3136 = 9,633,792 f
    float* att  = v + 9633792;         // 16*486*3136 = 24,385,536 f
    float* fold = att + 24385536;      // 9,633,792 f   (total ~175 MB)

    dim3 blk(256);
    // NHW/64 = 50176/64 = 784 position tiles
    gemm_ncp<<<dim3(784, 3), blk, 0, stream>>>(x, Wv, nullptr, v, 192);
    gemm_ncp<<<dim3(784, 8), blk, 0, stream>>>(x, Wa, ba, att, 486);
    fused_att_agg<<<1176, blk, 0, stream>>>(att, v, fold);  // 16*6*3136/256
    gemm_ncp<<<dim3(784, 3), blk, 0, stream>>>(fold, Wp, bp, out, 192);
}

// Round 3
// 260.378 us; speedup vs baseline: 2.1172x; 2.0055x over previous
//
#include <hip/hip_runtime.h>
#include <hip/hip_bf16.h>
#include <math.h>

#define HW 3136
#define NC 192
#define NHEADS 6
#define IMG 56
#define NATT 486
#define NATTP 512
#define ATT_SCALE 0.17677669529663687f  // 32^-0.5

typedef __attribute__((ext_vector_type(8))) short short8;
typedef __attribute__((ext_vector_type(8))) unsigned short ushort8;
typedef __attribute__((ext_vector_type(4))) float float4v;

__device__ __forceinline__ float bf2f(unsigned short u) {
    unsigned int x = ((unsigned int)u) << 16;
    return __builtin_bit_cast(float, x);
}
__device__ __forceinline__ unsigned short f2bf(float f) {
    __hip_bfloat16 h = __float2bfloat16(f);
    return __builtin_bit_cast(unsigned short, h);
}
__device__ __forceinline__ void gload_lds16(const void* g, void* l) {
    __builtin_amdgcn_global_load_lds((const __attribute__((address_space(1))) void*)g,
                                     (__attribute__((address_space(3))) void*)l, 16, 0, 0);
}

// x [16][192][3136] fp32 -> xt [50176][192] bf16 (channels-last). grid (784,3), block 256.
__global__ __launch_bounds__(256) void transpose_x(const float* __restrict__ x,
                                                   unsigned short* __restrict__ xt)
{
    __shared__ float tile[64][65];
    int bx = blockIdx.x;
    int n = (bx * 64) / HW;
    int hw0 = (bx * 64) % HW;
    int c0 = blockIdx.y * 64;
    int tl = threadIdx.x & 63, tg = threadIdx.x >> 6;
    const float* xn = x + (size_t)n * NC * HW;
#pragma unroll
    for (int i = 0; i < 16; ++i)
        tile[tg * 16 + i][tl] = xn[(size_t)(c0 + tg * 16 + i) * HW + hw0 + tl];
    __syncthreads();
    unsigned short* xp = xt + ((size_t)n * HW + hw0) * NC + c0;
#pragma unroll
    for (int i = 0; i < 16; ++i) {
        int hwr = tg * 16 + i;
        xp[(size_t)hwr * NC + tl] = f2bf(tile[tl][hwr]);
    }
}

// W [k][d] fp32 -> Wt [d][k] bf16 (Wa padded to 512 rows, zeros). grid 384, block 256.
__global__ __launch_bounds__(256) void prep_weights(
    const float* __restrict__ Wv, const float* __restrict__ Wa, const float* __restrict__ Wp,
    unsigned short* __restrict__ Wvt, unsigned short* __restrict__ Wat,
    unsigned short* __restrict__ Wpt)
{
    int idx = blockIdx.x * 256 + threadIdx.x;   // 192 * 512
    int k = idx >> 9, d = idx & 511;
    if (d < NC) {
        Wvt[(size_t)d * NC + k] = f2bf(Wv[(size_t)k * NC + d]);
        Wpt[(size_t)d * NC + k] = f2bf(Wp[(size_t)k * NC + d]);
    }
    Wat[(size_t)d * NC + k] = (d < NATT) ? f2bf(Wa[(size_t)k * NATT + d]) : (unsigned short)0;
}

// C[m][n] = sum_k A[m][k]*B[n][k], K=192, bf16 in, tile 64x64, 4 waves of 32x32.
// MODE 0: store bf16 C[m*192+n]            (v = xt x Wvt)
// MODE 1: store bf16 C[m*512+n] + bias[n]  (att = xt x Wat, n>=486 pad -> 0)
// MODE 2: store f32 out[img][m][phw] + bias[m], n = global position (out = Wpt x fold)
template<int MODE>
__global__ __launch_bounds__(256) void gemm_mfma(
    const unsigned short* __restrict__ A, const unsigned short* __restrict__ B,
    const float* __restrict__ bias, void* __restrict__ Cout)
{
    __shared__ __align__(16) unsigned short As[64 * 32];
    __shared__ __align__(16) unsigned short Bs[64 * 32];
    int t = threadIdx.x, lane = t & 63, wave = t >> 6;
    int m0 = blockIdx.y * 64, n0 = blockIdx.x * 64;
    int srow = lane >> 2, squad = lane & 3;
    const unsigned short* ga = A + (size_t)(m0 + wave * 16 + srow) * NC + squad * 8;
    const unsigned short* gb = B + (size_t)(n0 + wave * 16 + srow) * NC + squad * 8;
    unsigned short* la = As + wave * 512;
    unsigned short* lb = Bs + wave * 512;
    int fr = lane & 15, fq = lane >> 4;
    int wm = (wave >> 1) * 32, wn = (wave & 1) * 32;
    float4v acc[2][2] = {};

    for (int k0 = 0; k0 < NC; k0 += 32) {
        gload_lds16(ga + k0, la);
        gload_lds16(gb + k0, lb);
        __syncthreads();
        short8 af[2], bfv[2];
#pragma unroll
        for (int mi = 0; mi < 2; ++mi)
            af[mi] = *(const short8*)&As[(wm + mi * 16 + fr) * 32 + fq * 8];
#pragma unroll
        for (int ni = 0; ni < 2; ++ni)
            bfv[ni] = *(const short8*)&Bs[(wn + ni * 16 + fr) * 32 + fq * 8];
#pragma unroll
        for (int mi = 0; mi < 2; ++mi)
#pragma unroll
            for (int ni = 0; ni < 2; ++ni)
                acc[mi][ni] = __builtin_amdgcn_mfma_f32_16x16x32_bf16(
                    af[mi], bfv[ni], acc[mi][ni], 0, 0, 0);
        __syncthreads();
    }

#pragma unroll
    for (int mi = 0; mi < 2; ++mi)
#pragma unroll
        for (int ni = 0; ni < 2; ++ni)
#pragma unroll
            for (int r = 0; r < 4; ++r) {
                int m = m0 + wm + mi * 16 + fq * 4 + r;
                int n = n0 + wn + ni * 16 + fr;
                float val = acc[mi][ni][r];
                if (MODE == 0) {
                    ((unsigned short*)Cout)[(size_t)m * NC + n] = f2bf(val);
                } else if (MODE == 1) {
                    if (n < NATT) val += bias[n];
                    ((unsigned short*)Cout)[(size_t)m * NATTP + n] = f2bf(val);
                } else {
                    int img = n / HW, phw = n - img * HW;
                    ((float*)Cout)[(size_t)img * (NC * HW) + (size_t)m * HW + phw] =
                        val + bias[m];
                }
            }
}

// Fused softmax(l) + fold/unfold weight-combine (25-tap) + 32-ch aggregation.
// Channels-last bf16: att [nhw][512], v [nhw][192], fold [nhw][192].
__global__ __launch_bounds__(256) void fused_att_agg(
    const unsigned short* __restrict__ att, const unsigned short* __restrict__ v,
    unsigned short* __restrict__ fold)
{
    int idx = blockIdx.x * 256 + threadIdx.x;   // N*HEADS*HW
    int hw = idx % HW;
    int g = idx / HW;
    int head = g % NHEADS, n = g / NHEADS;
    int h = hw / IMG, w = hw % IMG;

    const unsigned short* attn = att + (size_t)n * HW * NATTP + head * 81;
    float wc[25];
#pragma unroll
    for (int d = 0; d < 25; ++d) wc[d] = 0.f;
#pragma unroll
    for (int k = 0; k < 9; ++k) {
        const int oky = k / 3 - 1, okx = k % 3 - 1;
        int hh = h - oky, ww = w - okx;
        if (hh < 0 || hh >= IMG || ww < 0 || ww >= IMG) continue;
        const unsigned short* ap = attn + (size_t)(hh * IMG + ww) * NATTP + k * 9;
        float a[9];
        float m = -1e30f;
#pragma unroll
        for (int l = 0; l < 9; ++l) {
            a[l] = bf2f(ap[l]);
            m = fmaxf(m, a[l]);
        }
        float s = 0.f;
#pragma unroll
        for (int l = 0; l < 9; ++l) {
            a[l] = __expf((a[l] - m) * ATT_SCALE);
            s += a[l];
        }
        float r = 1.f / s;
#pragma unroll
        for (int l = 0; l < 9; ++l) {
            const int dy = (l / 3 - 1) - oky + 2;
            const int dx = (l % 3 - 1) - okx + 2;
            wc[dy * 5 + dx] += a[l] * r;
        }
    }

    const unsigned short* vb = v + ((size_t)n * HW + hw) * NC + head * 32;
    float acc[32];
#pragma unroll
    for (int i = 0; i < 32; ++i) acc[i] = 0.f;
#pragma unroll
    for (int d = 0; d < 25; ++d) {
        const int dy = d / 5 - 2, dx = d % 5 - 2;
        int hh = h + dy, ww = w + dx;
        bool ok = (hh >= 0) & (hh < IMG) & (ww >= 0) & (ww < IMG);
        float wf = ok ? wc[d] : 0.f;
        const unsigned short* vp = vb + (ok ? (dy * IMG + dx) * NC : 0);
#pragma unroll
        for (int j = 0; j < 4; ++j) {
            ushort8 vv = *(const ushort8*)(vp + j * 8);
#pragma unroll
            for (int i = 0; i < 8; ++i)
                acc[j * 8 + i] += wf * bf2f(vv[i]);
        }
    }
    unsigned short* fo = fold + ((size_t)n * HW + hw) * NC + head * 32;
#pragma unroll
    for (int j = 0; j < 4; ++j) {
        ushort8 ov;
#pragma unroll
        for (int i = 0; i < 8; ++i) ov[i] = f2bf(acc[j * 8 + i]);
        *(ushort8*)(fo + j * 8) = ov;
    }
}

extern "C" void kernel_launch(void* const* d_in, const int* in_sizes, int n_in,
                              void* d_out, int out_size, void* d_ws, size_t ws_size,
                              hipStream_t stream)
{
    const float* x  = (const float*)d_in[0];
    const float* Wv = (const float*)d_in[1];
    const float* Wa = (const float*)d_in[2];
    const float* ba = (const float*)d_in[3];
    const float* Wp = (const float*)d_in[4];
    const float* bp = (const float*)d_in[5];
    float* out = (float*)d_out;

    unsigned short* xt    = (unsigned short*)d_ws;       // 50176*192
    unsigned short* vbf   = xt + 9633792;                // 50176*192
    unsigned short* attb  = vbf + 9633792;               // 50176*512
    unsigned short* foldb = attb + 25690112;             // 50176*192
    unsigned short* wvt   = foldb + 9633792;             // 192*192
    unsigned short* wat   = wvt + 36864;                 // 512*192
    unsigned short* wpt   = wat + 98304;                 // 192*192

    dim3 blk(256);
    prep_weights<<<384, blk, 0, stream>>>(Wv, Wa, Wp, wvt, wat, wpt);
    transpose_x<<<dim3(784, 3), blk, 0, stream>>>(x, xt);
    gemm_mfma<0><<<dim3(3, 784), blk, 0, stream>>>(xt, wvt, nullptr, vbf);
    gemm_mfma<1><<<dim3(8, 784), blk, 0, stream>>>(xt, wat, ba, attb);
    fused_att_agg<<<1176, blk, 0, stream>>>(attb, vbf, foldb);
    gemm_mfma<2><<<dim3(784, 3), blk, 0, stream>>>(wpt, foldb, bp, out);
}